// Round 11
// baseline (41.424 us; speedup 1.0000x reference)
//
#include <hip/hip_runtime.h>
#include <hip/hip_bf16.h>

// Segment mean: N values, sorted segment ids, NC segments.
// r11 = r5 structure (41.2us) with ONE change: int64 ids are read as
// stride-2 dword loads of the LOW words only -> requested bytes drop
// 192MB -> 128MB (cache-line traffic unchanged). Discriminates
// "VMEM-return requested-byte limit" vs "line-delivery limit".

#define VPT 16

typedef float fx4 __attribute__((ext_vector_type(4)));
typedef int   ix4 __attribute__((ext_vector_type(4)));

__global__ void seg_sum_kernel(const float* __restrict__ x,
                               const void* __restrict__ seg,
                               float* __restrict__ sums,
                               float* __restrict__ cnts,
                               int n) {
    const int* s32 = (const int*)seg;
    const long long* s64 = (const long long*)seg;
    // dtype sniff: int64 storage => int32 word [n-1] is a high word (0,
    // ids < 2^18). int32 storage => largest sorted id (nonzero).
    const bool is64 = (s32[n - 1] == 0);

    const long long base = (long long)(blockIdx.x * (long long)blockDim.x + threadIdx.x) * VPT;
    const int lane = threadIdx.x & 63;

    int ids[VPT];
    float vals[VPT];
    int nv = 0;
    if (base < n) {
        long long rem = (long long)n - base;
        nv = (rem >= VPT) ? VPT : (int)rem;
    }

    if (nv == VPT) {
        const fx4* xv = (const fx4*)(x + base);
        #pragma unroll
        for (int k = 0; k < 4; ++k) {
            fx4 a = xv[k];
            vals[4 * k]     = a.x;
            vals[4 * k + 1] = a.y;
            vals[4 * k + 2] = a.z;
            vals[4 * k + 3] = a.w;
        }
        if (is64) {
            // Low dword of each little-endian int64: dword index 2*(base+k).
            // 16 independent 4B loads -> half the requested bytes of dwordx4.
            const int* sd = (const int*)s64;
            #pragma unroll
            for (int k = 0; k < VPT; ++k) {
                ids[k] = sd[2 * (base + k)];
            }
        } else {
            const ix4* iv = (const ix4*)(s32 + base);
            #pragma unroll
            for (int k = 0; k < 4; ++k) {
                ix4 t = iv[k];
                ids[4 * k]     = t.x;
                ids[4 * k + 1] = t.y;
                ids[4 * k + 2] = t.z;
                ids[4 * k + 3] = t.w;
            }
        }
    } else {
        #pragma unroll
        for (int k = 0; k < VPT; ++k) {
            if (k < nv) {
                ids[k]  = is64 ? (int)s64[base + k] : s32[base + k];
                vals[k] = x[base + k];
            } else {
                ids[k]  = -1;
                vals[k] = 0.0f;
            }
        }
    }

    // Sequential run-merge within the thread; flush closed runs immediately.
    int   cur = (nv > 0) ? ids[0] : -1;
    float s   = (nv > 0) ? vals[0] : 0.0f;
    float c   = (nv > 0) ? 1.0f : 0.0f;
    #pragma unroll
    for (int k = 1; k < VPT; ++k) {
        if (k < nv) {
            if (ids[k] == cur) {
                s += vals[k];
                c += 1.0f;
            } else {
                atomicAdd(&sums[cur], s);
                atomicAdd(&cnts[cur], c);
                cur = ids[k];
                s = vals[k];
                c = 1.0f;
            }
        }
    }

    // Wave segmented scan over trailing runs. Sortedness makes the equality
    // guard exact: lid[i-off]==lid[i] implies all threads between share it.
    int lid = cur;
    #pragma unroll
    for (int off = 1; off < 64; off <<= 1) {
        float os = __shfl_up(s, off);
        float oc = __shfl_up(c, off);
        int  oid = __shfl_up(lid, off);
        if (lane >= off && oid == lid) {
            s += os;
            c += oc;
        }
    }

    // Chain-end lanes emit.
    int nid = __shfl_down(lid, 1);
    bool emit = (lid >= 0) && ((lane == 63) || (nid != lid));
    if (emit) {
        atomicAdd(&sums[lid], s);
        atomicAdd(&cnts[lid], c);
    }
}

__global__ void finalize_kernel(float* __restrict__ out,
                                const float* __restrict__ sums,
                                const float* __restrict__ cnts,
                                int nc) {
    int cidx = blockIdx.x * blockDim.x + threadIdx.x;
    if (cidx < nc) {
        float cv = cnts[cidx];
        out[cidx] = (cv > 0.0f) ? (sums[cidx] / cv) : 0.0f;
    }
}

extern "C" void kernel_launch(void* const* d_in, const int* in_sizes, int n_in,
                              void* d_out, int out_size, void* d_ws, size_t ws_size,
                              hipStream_t stream) {
    const float* x = (const float*)d_in[0];
    const void* seg = d_in[1];
    const int n = in_sizes[0];     // 16777216
    const int nc = out_size;       // 262144

    float* sums = (float*)d_ws;          // [nc]
    float* cnts = (float*)d_ws + nc;     // [nc]
    float* out  = (float*)d_out;

    // Re-zero accumulators every call (harness does not re-poison between
    // graph replays).
    (void)hipMemsetAsync(sums, 0, (size_t)2 * nc * sizeof(float), stream);

    const int block = 256;
    const long long elems_per_block = (long long)block * VPT;
    const int grid = (int)((n + elems_per_block - 1) / elems_per_block);
    seg_sum_kernel<<<grid, block, 0, stream>>>(x, seg, sums, cnts, n);

    const int fgrid = (nc + block - 1) / block;
    finalize_kernel<<<fgrid, block, 0, stream>>>(out, sums, cnts, nc);
}